// Round 5
// baseline (413.227 us; speedup 1.0000x reference)
//
#include <hip/hip_runtime.h>
#include <hip/hip_bf16.h>
#include <cstring>

#define N_NODES 50000
#define N_EDGES 800000
#define IN_CH 128
#define NG 500
#define OUT_ELEMS 9782000
#define NBUCK 196  // 256-node buckets: ceil(50000/256)
#define DR 32      // rows/block for layer-1 gemm tile

using bf16 = __hip_bfloat16;
typedef unsigned short u16;
typedef unsigned int u32;
typedef long long i64;
typedef unsigned long long u64;

__device__ __forceinline__ float b2f(bf16 v) { return __bfloat162float(v); }
__device__ __forceinline__ float tofl(float v) { return v; }
__device__ __forceinline__ float tofl(bf16 v) { return __bfloat162float(v); }
__device__ __forceinline__ float ldflt(const void* p, int i, int f32) {
  return f32 ? ((const float*)p)[i] : b2f(((const bf16*)p)[i]);
}
__device__ __forceinline__ int ldedge(const void* p, int i, int is64) {
  return is64 ? (int)((const i64*)p)[i] : ((const int*)p)[i];
}
__device__ __forceinline__ float sane(float v) {
  if (!isfinite(v)) return 0.f;
  return fminf(fmaxf(v, -65504.f), 65504.f);
}
__device__ __forceinline__ float lrelu(float x) { return x > 0.f ? x : 0.2f * x; }
// exact bf16->f32 unpack of a 2xbf16 word (low elem = low 16 bits)
__device__ __forceinline__ float bflo(u32 u) { return __uint_as_float(u << 16); }
__device__ __forceinline__ float bfhi(u32 u) { return __uint_as_float(u & 0xffff0000u); }

__device__ __forceinline__ float wsum(float v) {
#pragma unroll
  for (int o = 32; o > 0; o >>= 1) v += __shfl_xor(v, o, 64);
  return v;
}

// d_out is FLOAT32, 9,782,000 elems:
//   xhat@0 (6,400,000) | ehat@6,400,000 (150,000) | zreg@6,550,000 (3,200,000)
//   emb@9,750,000 (32,000)
// Scratch arena (base = d_ws if ws_size>=17.1MB else d_out; in fallback it sits
// inside the xhat region, which only the FINAL dec kernel writes):
//   deg/ss2@0 (200,000) | bcur/sd2@200,000 (200,000)
//   offs@400,000 (200,016) | part@600,016 (256) | flags@600,272 (64)
//   ss@600,448 (200,000) | sd@800,448 (200,000) | csr@1,000,448 (3,200,000)
//   hbuf(bf16)@4,200,448 (6,400,000) | tmp(u64)/hbuf2@10,600,448 (6,400,000)
//   -> ends 17,000,448 < 25,600,000

__global__ void fillsig_kernel(float* __restrict__ out, int n, float v) {
  int i = blockIdx.x * 256 + threadIdx.x;
  if (i < n) out[i] = v;
}

// ---- prep: zero deg + dtype sniffers (direct writes, no finalize pass) ----
__global__ __launch_bounds__(256) void prep_kernel(const u16* __restrict__ xb,
                                                   const int* __restrict__ ei32,
                                                   int* __restrict__ deg,
                                                   int* __restrict__ fl) {
  int bid = blockIdx.x, tid = threadIdx.x;
  if (bid < 196) {
    int i = bid * 256 + tid;
    if (i < N_NODES) deg[i] = 0;
    return;
  }
  __shared__ int c;
  if (tid == 0) c = 0;
  __syncthreads();
  int cnt = 0;
  if (bid == 196) {
#pragma unroll 4
    for (int k = 0; k < 32; ++k) {
      int i = tid + 256 * k;
      u16 u = xb[2 * i];
      int e = (u >> 7) & 0xFF;
      if (e != 0 && (e < 90 || e > 150)) ++cnt;
    }
  } else {
#pragma unroll 4
    for (int k = 0; k < 32; ++k) {
      int i = tid + 256 * k;
      if (ei32[2 * i + 1] == 0) ++cnt;
    }
  }
  atomicAdd(&c, cnt);
  __syncthreads();
  if (tid == 0) fl[bid == 196 ? 7 : 6] = c;
}

// ---- CSR build ----
__global__ void hist_kernel(const void* __restrict__ ei, const int* __restrict__ fl,
                            int* __restrict__ deg) {
  int is64 = fl[6] > 4000;
  int e = blockIdx.x * 256 + threadIdx.x;
  if (e < N_EDGES) {
    unsigned d = (unsigned)ldedge(ei, N_EDGES + e, is64);
    if (d < N_NODES) atomicAdd(&deg[d], 1);
  }
}

__global__ __launch_bounds__(1024) void scan1_kernel(const int* __restrict__ deg,
                                                     int* __restrict__ offs,
                                                     int* __restrict__ part, int n) {
  __shared__ int sm[1024];
  int t = threadIdx.x;
  int idx = blockIdx.x * 1024 + t;
  int v = (idx < n) ? deg[idx] : 0;
  sm[t] = v;
  __syncthreads();
  for (int off = 1; off < 1024; off <<= 1) {
    int add = (t >= off) ? sm[t - off] : 0;
    __syncthreads();
    sm[t] += add;
    __syncthreads();
  }
  if (idx < n) offs[idx] = sm[t] - v;
  if (t == 1023) part[blockIdx.x] = sm[1023];
}

// finalizes offs (folding the serial partial-prefix), sets offs[n], and
// initializes the 256-node-bucket cursors. part[] holds raw per-1024 sums.
__global__ void scan3_kernel(int* __restrict__ offs, const int* __restrict__ part,
                             int* __restrict__ bcur, int n) {
  __shared__ int pbase;
  int b = blockIdx.x;
  int tid = threadIdx.x;
  if (tid == 0) {
    int bucket = b >> 2;  // (b*256)>>10, constant within block
    int run = 0;
    for (int q = 0; q < bucket; ++q) run += part[q];
    pbase = run;
  }
  __syncthreads();
  int i = b * 256 + tid;
  if (i < n) {
    int v = offs[i] + pbase;
    offs[i] = v;
    if ((i & 255) == 0) bcur[i >> 8] = v;
  }
  if (i == 0) {
    int run = 0;
    for (int q = 0; q < 49; ++q) run += part[q];
    offs[n] = run;
  }
}

// Phase B: bucket-grouped edge records (256-node buckets).
#define BCHUNK 4096
__global__ __launch_bounds__(256) void bucket_kernel(const void* __restrict__ ei,
                                                     const int* __restrict__ fl,
                                                     int* __restrict__ bcur,
                                                     u64* __restrict__ tmp) {
  __shared__ int hist[NBUCK], run[NBUCK], gbase[NBUCK];
  int tid = threadIdx.x;
  if (tid < NBUCK) { hist[tid] = 0; run[tid] = 0; }
  __syncthreads();
  int is64 = fl[6] > 4000;
  int base = blockIdx.x * BCHUNK;
#pragma unroll
  for (int k = 0; k < 16; ++k) {
    int e = base + k * 256 + tid;
    if (e < N_EDGES) {
      unsigned d = (unsigned)ldedge(ei, N_EDGES + e, is64);
      if (d < N_NODES) atomicAdd(&hist[d >> 8], 1);
    }
  }
  __syncthreads();
  if (tid < NBUCK) {
    int h = hist[tid];
    gbase[tid] = h ? atomicAdd(&bcur[tid], h) : 0;
  }
  __syncthreads();
#pragma unroll
  for (int k = 0; k < 16; ++k) {
    int e = base + k * 256 + tid;
    if (e < N_EDGES) {
      unsigned d = (unsigned)ldedge(ei, N_EDGES + e, is64);
      if (d < N_NODES) {
        unsigned s = (unsigned)ldedge(ei, e, is64);
        if (s >= N_NODES) s = 0;  // keep count consistent with deg histogram
        int pos = gbase[d >> 8] + atomicAdd(&run[d >> 8], 1);
        tmp[pos] = ((u64)s << 32) | (u64)d;
      }
    }
  }
}

// ---- layer-1 GEMM body: 32 rows/block, 8 rows/wave, lane = out col ----
template <int FIN, typename FT>
__device__ void gemm32_compute(float (&xl)[DR][FIN], const void* Wv, const void* asv,
                               const void* adv, bf16* __restrict__ h, float* __restrict__ ss,
                               float* __restrict__ sd, int rbase) {
  const FT* W = (const FT*)Wv;
  const FT* as_ = (const FT*)asv;
  const FT* ad_ = (const FT*)adv;
  int lane = threadIdx.x & 63, w = threadIdx.x >> 6;
  int r0 = w * 8;
  float a_s = tofl(as_[lane]), a_d = tofl(ad_[lane]);
  float acc[8];
#pragma unroll
  for (int r = 0; r < 8; ++r) acc[r] = 0.f;
  for (int k = 0; k < FIN; k += 4) {
    float w0 = tofl(W[(k + 0) * 64 + lane]);
    float w1 = tofl(W[(k + 1) * 64 + lane]);
    float w2 = tofl(W[(k + 2) * 64 + lane]);
    float w3 = tofl(W[(k + 3) * 64 + lane]);
#pragma unroll
    for (int r = 0; r < 8; ++r) {
      const float4 xv = *(const float4*)&xl[r0 + r][k];
      acc[r] = fmaf(xv.x, w0, acc[r]);
      acc[r] = fmaf(xv.y, w1, acc[r]);
      acc[r] = fmaf(xv.z, w2, acc[r]);
      acc[r] = fmaf(xv.w, w3, acc[r]);
    }
  }
#pragma unroll
  for (int r = 0; r < 8; ++r) {
    int g = rbase + r0 + r;
    if (g < N_NODES) {
      float a = sane(acc[r]);
      h[g * 64 + lane] = __float2bfloat16(a);
      float vs = wsum(a * a_s);
      float vd = wsum(a * a_d);
      if (lane == 0) { ss[g] = sane(vs); sd[g] = sane(vd); }
    }
  }
}

// ---- FUSED: scatter2 (blocks 0..195) + layer-1 GEMM (blocks 196..)
// scatter and the x@W1 GEMM are independent; overlapping hides scatter latency.
__global__ __launch_bounds__(256) void scatter_gemm_kernel(
    const u64* __restrict__ tmp, const int* __restrict__ offs, int* __restrict__ csr,
    const void* __restrict__ xin, const void* __restrict__ W, const void* __restrict__ asrc,
    const void* __restrict__ adst, const int* __restrict__ fl, bf16* __restrict__ h,
    float* __restrict__ ss, float* __restrict__ sd) {
  __shared__ float xl[DR][IN_CH];  // 16 KB; scatter blocks reuse first 1 KB
  int bid = blockIdx.x, tid = threadIdx.x;
  if (bid < NBUCK) {
    int* lcur = (int*)&xl[0][0];
    if (tid < 256) lcur[tid] = 0;
    __syncthreads();
    int nodelo = bid << 8;
    int beg = offs[nodelo];
    int end = offs[min(nodelo + 256, N_NODES)];
    for (int i = beg + tid; i < end; i += 256) {
      u64 v = tmp[i];
      int d = (int)(v & 0xFFFFFFFFu);
      int s = (int)(v >> 32);
      unsigned li = (unsigned)(d - nodelo);
      if (li < 256) {
        int pos = offs[d] + atomicAdd(&lcur[li], 1);
        if ((unsigned)pos < N_EDGES) csr[pos] = s;
      }
    }
    return;
  }
  int wf = fl[7] > 2000;
  int rbase = (bid - NBUCK) * DR;
  for (int i = tid; i < DR * IN_CH; i += 256) {
    int rr = i / IN_CH, cc = i % IN_CH;
    int g = rbase + rr;
    xl[rr][cc] = (g < N_NODES) ? ldflt(xin, g * IN_CH + cc, wf) : 0.f;
  }
  __syncthreads();
  if (wf)
    gemm32_compute<IN_CH, float>(xl, W, asrc, adst, h, ss, sd, rbase);
  else
    gemm32_compute<IN_CH, bf16>(xl, W, asrc, adst, h, ss, sd, rbase);
}

// ---- GAT softmax-aggregate, TWO nodes per wave, 4 channels per lane ----
// Lanes 0-31 serve node dA, 32-63 serve dB. Within a half: 16-lane groups
// (grp = bit4) take alternating edges; each lane loads a u64 (4 bf16 ch) of
// its edge's h row. Doubles bytes/outstanding-load vs u32. After the edge
// loop, grp0/grp1 partial sums are combined via shfl_xor(16). Self term is
// added in grp0 only. FMA order per channel: even/odd edge interleave (pure
// f32 reorder vs before; noise-level).
__device__ __forceinline__ void agg_node2q(const bf16* __restrict__ h,
                                           const float* __restrict__ ss,
                                           const float* __restrict__ sd,
                                           const int* __restrict__ offs,
                                           const int* __restrict__ csr, int d, int lane,
                                           float (&acc4)[4]) {
  int hl = lane & 31;         // edge slot within the 32-edge window
  int hbase = lane & 32;      // own half's lane base
  int slot = lane & 15;       // u64 slot within the 128B row
  int grp = (lane >> 4) & 1;  // edge-pair subgroup
  float sdd = sd[d];
  int beg = offs[d], end = offs[d + 1];
  beg = max(0, min(beg, N_EDGES));
  end = max(beg, min(end, N_EDGES));
  float wself = __expf(fminf(lrelu(ss[d] + sdd), 60.f));
  u64 uself = ((const u64*)h)[d * 16 + slot];
  u32 slo = (u32)uself, shi = (u32)(uself >> 32);
  if (grp == 0) {
    acc4[0] = bflo(slo) * wself;
    acc4[1] = bfhi(slo) * wself;
    acc4[2] = bflo(shi) * wself;
    acc4[3] = bfhi(shi) * wself;
  } else {
    acc4[0] = acc4[1] = acc4[2] = acc4[3] = 0.f;
  }
  float dpart = (hl == 0) ? wself : 0.f;
  for (int cb = beg; cb < end; cb += 32) {
    int j = cb + hl;
    int s = 0;
    float wv = 0.f;
    if (j < end) {
      s = csr[j];
      s = ((unsigned)s < N_NODES) ? s : 0;
      wv = __expf(fminf(lrelu(ss[s] + sdd), 60.f));
    }
    dpart += wv;
    int cnt = min(32, end - cb);
    {  // batch A: edges 0..15 (8 rounds x 2 edges)
      u64 hv[8];
      float wq[8];
#pragma unroll
      for (int q = 0; q < 8; ++q) {
        int eidx = 2 * q + grp;
        int sq = __shfl(s, hbase + eidx, 64);
        wq[q] = __shfl(wv, hbase + eidx, 64);
        hv[q] = (eidx < cnt) ? ((const u64*)h)[sq * 16 + slot] : 0ull;
      }
#pragma unroll
      for (int q = 0; q < 8; ++q) {
        u32 lo = (u32)hv[q], hi = (u32)(hv[q] >> 32);
        acc4[0] = fmaf(bflo(lo), wq[q], acc4[0]);
        acc4[1] = fmaf(bfhi(lo), wq[q], acc4[1]);
        acc4[2] = fmaf(bflo(hi), wq[q], acc4[2]);
        acc4[3] = fmaf(bfhi(hi), wq[q], acc4[3]);
      }
    }
    if (cnt > 16) {  // batch B: edges 16..31
      u64 hv[8];
      float wq[8];
#pragma unroll
      for (int q = 0; q < 8; ++q) {
        int eidx = 16 + 2 * q + grp;
        int sq = __shfl(s, hbase + eidx, 64);
        wq[q] = __shfl(wv, hbase + eidx, 64);
        hv[q] = (eidx < cnt) ? ((const u64*)h)[sq * 16 + slot] : 0ull;
      }
#pragma unroll
      for (int q = 0; q < 8; ++q) {
        u32 lo = (u32)hv[q], hi = (u32)(hv[q] >> 32);
        acc4[0] = fmaf(bflo(lo), wq[q], acc4[0]);
        acc4[1] = fmaf(bfhi(lo), wq[q], acc4[1]);
        acc4[2] = fmaf(bflo(hi), wq[q], acc4[2]);
        acc4[3] = fmaf(bfhi(hi), wq[q], acc4[3]);
      }
    }
  }
  // combine grp0/grp1 partials (lane i <-> i^16, stays within the half)
#pragma unroll
  for (int c = 0; c < 4; ++c) acc4[c] += __shfl_xor(acc4[c], 16, 64);
  // half-wide (32-lane) reduction of the denominator
#pragma unroll
  for (int o = 16; o > 0; o >>= 1) dpart += __shfl_xor(dpart, o, 64);
  float den = dpart + 1e-16f;
#pragma unroll
  for (int c = 0; c < 4; ++c) acc4[c] = acc4[c] / den;
}

// ---- 4-row GEMM + scores epilogue (any single wave) ----
template <typename FT>
__device__ void gemm4_compute(float (&xl)[4][64], const void* Wv, const void* asv,
                              const void* adv, bf16* __restrict__ h, float* __restrict__ ss,
                              float* __restrict__ sd, int rbase) {
  const FT* W = (const FT*)Wv;
  const FT* as_ = (const FT*)asv;
  const FT* ad_ = (const FT*)adv;
  int lane = threadIdx.x & 63;
  float a_s = tofl(as_[lane]), a_d = tofl(ad_[lane]);
  float acc0 = 0.f, acc1 = 0.f, acc2 = 0.f, acc3 = 0.f;
  for (int k = 0; k < 64; ++k) {
    float wk = tofl(W[k * 64 + lane]);
    acc0 = fmaf(xl[0][k], wk, acc0);
    acc1 = fmaf(xl[1][k], wk, acc1);
    acc2 = fmaf(xl[2][k], wk, acc2);
    acc3 = fmaf(xl[3][k], wk, acc3);
  }
  float acc[4] = {sane(acc0), sane(acc1), sane(acc2), sane(acc3)};
#pragma unroll
  for (int j = 0; j < 4; ++j) {
    int g = rbase + j;
    h[g * 64 + lane] = __float2bfloat16(acc[j]);
    float vs = wsum(acc[j] * a_s);
    float vd = wsum(acc[j] * a_d);
    if (lane == 0) { ss[g] = sane(vs); sd[g] = sane(vd); }
  }
}

// ---- 4-row linear epilogue (any single wave) ----
template <typename FT>
__device__ void lin4_compute(float (&xl)[4][64], const void* Wv, const void* bv,
                             float* __restrict__ zio, int rbase) {
  const FT* W = (const FT*)Wv;
  const FT* b = (const FT*)bv;
  int lane = threadIdx.x & 63;
  float bl = tofl(b[lane]);
  float acc0 = bl, acc1 = bl, acc2 = bl, acc3 = bl;
  for (int k = 0; k < 64; ++k) {
    float wk = tofl(W[k * 64 + lane]);
    acc0 = fmaf(xl[0][k], wk, acc0);
    acc1 = fmaf(xl[1][k], wk, acc1);
    acc2 = fmaf(xl[2][k], wk, acc2);
    acc3 = fmaf(xl[3][k], wk, acc3);
  }
  float acc[4] = {sane(acc0), sane(acc1), sane(acc2), sane(acc3)};
#pragma unroll
  for (int j = 0; j < 4; ++j) zio[(rbase + j) * 64 + lane] = acc[j];
}

// ---- FUSED layer-1 aggregate (+relu) + layer-2 GEMM: 8 nodes/block ----
__global__ __launch_bounds__(256) void agg_gemm_kernel(
    const bf16* __restrict__ hL, const float* __restrict__ ssL, const float* __restrict__ sdL,
    const int* __restrict__ offs, const int* __restrict__ csr, const void* __restrict__ bias,
    const int* __restrict__ fl, const void* __restrict__ W2, const void* __restrict__ as2,
    const void* __restrict__ ad2, bf16* __restrict__ hOut, float* __restrict__ ssOut,
    float* __restrict__ sdOut) {
  __shared__ float o1l[8][64];
  int wf = fl[7] > 2000;
  int lane = threadIdx.x & 63, w = threadIdx.x >> 6;
  int half = lane >> 5, slot = lane & 15;
  int rbase = blockIdx.x * 8;
  int d = rbase + 2 * w + half;
  float acc4[4];
  agg_node2q(hL, ssL, sdL, offs, csr, d, lane, acc4);
#pragma unroll
  for (int c = 0; c < 4; ++c) {
    float bl = ldflt(bias, 4 * slot + c, wf);
    o1l[2 * w + half][4 * slot + c] = sane(fmaxf(acc4[c] + bl, 0.f));  // relu
  }
  __syncthreads();
  if (w < 2) {
    float(&sub)[4][64] = *reinterpret_cast<float(*)[4][64]>(&o1l[4 * w]);
    if (wf)
      gemm4_compute<float>(sub, W2, as2, ad2, hOut, ssOut, sdOut, rbase + 4 * w);
    else
      gemm4_compute<bf16>(sub, W2, as2, ad2, hOut, ssOut, sdOut, rbase + 4 * w);
  }
}

// ---- FUSED layer-2 aggregate + encoder linear: 8 nodes/block ----
__global__ __launch_bounds__(256) void agg_lin_kernel(
    const bf16* __restrict__ hL, const float* __restrict__ ssL, const float* __restrict__ sdL,
    const int* __restrict__ offs, const int* __restrict__ csr, const void* __restrict__ bias,
    const int* __restrict__ fl, const void* __restrict__ linW, const void* __restrict__ linb,
    float* __restrict__ zreg) {
  __shared__ float o2l[8][64];
  int wf = fl[7] > 2000;
  int lane = threadIdx.x & 63, w = threadIdx.x >> 6;
  int half = lane >> 5, slot = lane & 15;
  int rbase = blockIdx.x * 8;
  int d = rbase + 2 * w + half;
  float acc4[4];
  agg_node2q(hL, ssL, sdL, offs, csr, d, lane, acc4);
#pragma unroll
  for (int c = 0; c < 4; ++c) {
    float bl = ldflt(bias, 4 * slot + c, wf);
    o2l[2 * w + half][4 * slot + c] = sane(acc4[c] + bl);  // no relu
  }
  __syncthreads();
  if (w < 2) {
    float(&sub)[4][64] = *reinterpret_cast<float(*)[4][64]>(&o2l[4 * w]);
    if (wf)
      lin4_compute<float>(sub, linW, linb, zreg, rbase + 4 * w);
    else
      lin4_compute<bf16>(sub, linW, linb, zreg, rbase + 4 * w);
  }
}

// ---- FUSED decoders (16 rows/block, 4 rows/wave) + global mean pool ----
// dec: round-2-proven structure (VGPR ~48, high occupancy) + k-quad weight
// loads / float4 LDS reads. t1 rows are wave-private -> no inner barriers.
// pool: blocks >= 3125 do the segmented mean (independent, reads zreg only).
template <typename FT>
__device__ void dec16_compute(float (&zl)[16][64], float (&t1)[16][68], float (&W2l)[192],
                              const void* xW1v, const void* xb1v, const void* xW2v,
                              const void* xb2v, const void* eW1v, const void* eb1v,
                              const void* eb2v, float* __restrict__ xout,
                              float* __restrict__ eout, int rbase) {
  const FT* xW1 = (const FT*)xW1v;
  const FT* xb1 = (const FT*)xb1v;
  const FT* xW2 = (const FT*)xW2v;
  const FT* xb2 = (const FT*)xb2v;
  const FT* eW1 = (const FT*)eW1v;
  const FT* eb1 = (const FT*)eb1v;
  const FT* eb2 = (const FT*)eb2v;
  int lane = threadIdx.x & 63, w = threadIdx.x >> 6;
  int r0 = w * 4;
  // ---- x decoder phase 1: t1 = relu(z @ xmW1 + b1) ----
  {
    float b1l = tofl(xb1[lane]);
    float acc[4] = {b1l, b1l, b1l, b1l};
    for (int k = 0; k < 64; k += 4) {
      float w0 = tofl(xW1[(k + 0) * 64 + lane]);
      float w1 = tofl(xW1[(k + 1) * 64 + lane]);
      float w2 = tofl(xW1[(k + 2) * 64 + lane]);
      float w3 = tofl(xW1[(k + 3) * 64 + lane]);
#pragma unroll
      for (int r = 0; r < 4; ++r) {
        const float4 zv = *(const float4*)&zl[r0 + r][k];
        acc[r] = fmaf(zv.x, w0, acc[r]);
        acc[r] = fmaf(zv.y, w1, acc[r]);
        acc[r] = fmaf(zv.z, w2, acc[r]);
        acc[r] = fmaf(zv.w, w3, acc[r]);
      }
    }
#pragma unroll
    for (int r = 0; r < 4; ++r) t1[r0 + r][lane] = fmaxf(acc[r], 0.f);
  }
  // ---- x decoder phase 2: xout = t1 @ xmW2 + b2 (64->128) ----
  {
    float b2a = tofl(xb2[lane]), b2b = tofl(xb2[64 + lane]);
    float a0[4] = {b2a, b2a, b2a, b2a};
    float a1[4] = {b2b, b2b, b2b, b2b};
    for (int k = 0; k < 64; k += 4) {
      float wa0 = tofl(xW2[(k + 0) * 128 + lane]), wb0 = tofl(xW2[(k + 0) * 128 + 64 + lane]);
      float wa1 = tofl(xW2[(k + 1) * 128 + lane]), wb1 = tofl(xW2[(k + 1) * 128 + 64 + lane]);
      float wa2 = tofl(xW2[(k + 2) * 128 + lane]), wb2 = tofl(xW2[(k + 2) * 128 + 64 + lane]);
      float wa3 = tofl(xW2[(k + 3) * 128 + lane]), wb3 = tofl(xW2[(k + 3) * 128 + 64 + lane]);
#pragma unroll
      for (int r = 0; r < 4; ++r) {
        const float4 tv = *(const float4*)&t1[r0 + r][k];
        a0[r] = fmaf(tv.x, wa0, a0[r]);
        a1[r] = fmaf(tv.x, wb0, a1[r]);
        a0[r] = fmaf(tv.y, wa1, a0[r]);
        a1[r] = fmaf(tv.y, wb1, a1[r]);
        a0[r] = fmaf(tv.z, wa2, a0[r]);
        a1[r] = fmaf(tv.z, wb2, a1[r]);
        a0[r] = fmaf(tv.w, wa3, a0[r]);
        a1[r] = fmaf(tv.w, wb3, a1[r]);
      }
    }
#pragma unroll
    for (int r = 0; r < 4; ++r) {
      int g = rbase + r0 + r;
      xout[g * 128 + lane] = sane(a0[r]);
      xout[g * 128 + 64 + lane] = sane(a1[r]);
    }
  }
  // ---- e decoder phase 1: t1 = relu(z @ emW1 + b1) (wave-private overwrite) ----
  {
    float b1l = tofl(eb1[lane]);
    float acc[4] = {b1l, b1l, b1l, b1l};
    for (int k = 0; k < 64; k += 4) {
      float w0 = tofl(eW1[(k + 0) * 64 + lane]);
      float w1 = tofl(eW1[(k + 1) * 64 + lane]);
      float w2 = tofl(eW1[(k + 2) * 64 + lane]);
      float w3 = tofl(eW1[(k + 3) * 64 + lane]);
#pragma unroll
      for (int r = 0; r < 4; ++r) {
        const float4 zv = *(const float4*)&zl[r0 + r][k];
        acc[r] = fmaf(zv.x, w0, acc[r]);
        acc[r] = fmaf(zv.y, w1, acc[r]);
        acc[r] = fmaf(zv.z, w2, acc[r]);
        acc[r] = fmaf(zv.w, w3, acc[r]);
      }
    }
#pragma unroll
    for (int r = 0; r < 4; ++r) t1[r0 + r][lane] = fmaxf(acc[r], 0.f);
  }
  // ---- e decoder phase 2: eout = t1 @ emW2 + b2 (64->3) ----
  {
    int jj = lane >> 4, c = lane & 15;
    if (c < 3) {
      int row = r0 + jj;
      float a = tofl(eb2[c]);
#pragma unroll 4
      for (int k = 0; k < 64; ++k) a = fmaf(t1[row][k], W2l[k * 3 + c], a);
      eout[(rbase + row) * 3 + c] = sane(a);
    }
  }
}

#define DECB 3125  // dec blocks: 50000/16
__global__ __launch_bounds__(256) void dec_pool_kernel(
    const float* __restrict__ z, const void* __restrict__ xmW1, const void* __restrict__ xmb1,
    const void* __restrict__ xmW2, const void* __restrict__ xmb2, const void* __restrict__ emW1,
    const void* __restrict__ emb1, const void* __restrict__ emW2, const void* __restrict__ emb2,
    const void* __restrict__ batch, const int* __restrict__ fl, float* __restrict__ xout,
    float* __restrict__ eout, float* __restrict__ emb) {
  __shared__ float zl[16][64];
  __shared__ float t1[16][68];  // stride 68: 16B-aligned rows + conflict-free e-phase2
  __shared__ float W2l[192];
  int tid = threadIdx.x;
  if (blockIdx.x >= DECB) {
    // ---- pool branch (reuses zl/t1 LDS) ----
    float(&sm)[4][64] = *reinterpret_cast<float(*)[4][64]>(&zl[0][0]);
    int* bounds = (int*)&t1[0][0];
    int g = blockIdx.x - DECB;
    int lane = tid & 63, w = tid >> 6;
    int is64 = fl[6] > 4000;
    if (tid < 2) {
      int target = g + tid;  // lower_bound(batch, target)
      int lo = 0, hi = N_NODES;
      while (lo < hi) {
        int mid = (lo + hi) >> 1;
        if (ldedge(batch, mid, is64) < target) lo = mid + 1; else hi = mid;
      }
      bounds[tid] = lo;
    }
    __syncthreads();
    int beg = bounds[0], end = bounds[1];
    float acc = 0.f;
    for (int r = beg + w; r < end; r += 4) acc += z[r * 64 + lane];
    sm[w][lane] = acc;
    __syncthreads();
    if (w == 0) {
      float v = sm[0][lane] + sm[1][lane] + sm[2][lane] + sm[3][lane];
      float cnt = (float)max(end - beg, 1);
      emb[g * 64 + lane] = sane(v / cnt);
    }
    return;
  }
  int wf = fl[7] > 2000;
  int rbase = blockIdx.x * 16;
  for (int i = tid; i < 1024; i += 256) zl[i >> 6][i & 63] = z[rbase * 64 + i];
  if (tid < 192) W2l[tid] = wf ? ((const float*)emW2)[tid] : b2f(((const bf16*)emW2)[tid]);
  __syncthreads();
  if (wf)
    dec16_compute<float>(zl, t1, W2l, xmW1, xmb1, xmW2, xmb2, emW1, emb1, emb2, xout, eout, rbase);
  else
    dec16_compute<bf16>(zl, t1, W2l, xmW1, xmb1, xmW2, xmb2, emW1, emb1, emb2, xout, eout, rbase);
}

extern "C" void kernel_launch(void* const* d_in, const int* in_sizes, int n_in,
                              void* d_out, int out_size, void* d_ws, size_t ws_size,
                              hipStream_t stream) {
  float* outf = (float*)d_out;
  if (out_size != OUT_ELEMS) {
    float sig = 2048.0f + fminf((float)out_size * 1e-4f, 999.f);
    fillsig_kernel<<<(out_size + 255) / 256, 256, 0, stream>>>(outf, out_size, sig);
    return;
  }
  if (n_in < 22 || in_sizes[0] != N_NODES * IN_CH || in_sizes[1] != 2 * N_EDGES) {
    fillsig_kernel<<<(out_size + 255) / 256, 256, 0, stream>>>(outf, out_size, 5000.f);
    return;
  }

  const void* x = d_in[0];
  const void* ei = d_in[1];
  const void* batch = d_in[2];
  const void* W1 = d_in[4];
  const void* as1 = d_in[5];
  const void* ad1 = d_in[6];
  const void* b1 = d_in[7];
  const void* W2 = d_in[8];
  const void* as2 = d_in[9];
  const void* ad2 = d_in[10];
  const void* b2 = d_in[11];
  const void* linW = d_in[12];
  const void* linb = d_in[13];
  const void* xmW1 = d_in[14];
  const void* xmb1 = d_in[15];
  const void* xmW2 = d_in[16];
  const void* xmb2 = d_in[17];
  const void* emW1 = d_in[18];
  const void* emb1 = d_in[19];
  const void* emW2 = d_in[20];
  const void* emb2 = d_in[21];

  float* xhat = outf;                 // [50000,128] f32
  float* ehat = outf + 6400000;       // [50000,3]
  float* zreg = outf + 6550000;       // [50000,64]  z (f32)
  float* emb = outf + 9750000;        // [500,64]

  bool usews = ws_size >= (size_t)17100000;
  char* base = usews ? (char*)d_ws : (char*)d_out;  // scratch in xhat region if !usews
  int* deg = (int*)(base + 0);
  int* bcur = (int*)(base + 200000);
  int* offs = (int*)(base + 400000);
  int* part = (int*)(base + 600016);
  int* flags = (int*)(base + 600272);
  float* ssb = (float*)(base + 600448);
  float* sdb = (float*)(base + 800448);
  int* csr = (int*)(base + 1000448);
  bf16* hbuf = (bf16*)(base + 4200448);
  u64* tmp = (u64*)(base + 10600448);  // ends 17,000,448 < 25,600,000
  // dead-region reuse after scatter:
  float* ss2 = (float*)(base + 0);       // over deg
  float* sd2 = (float*)(base + 200000);  // over bcur
  bf16* hbuf2 = (bf16*)(base + 10600448);  // over tmp

  int err = 0, idx = 0;
  (void)hipGetLastError();
#define CK()                                                                       \
  do {                                                                             \
    ++idx;                                                                         \
    hipError_t e_ = hipGetLastError();                                             \
    if (e_ != hipSuccess && err == 0) err = 8192 + idx * 256 + ((int)e_ & 3) * 64; \
  } while (0)

  // 1: zero deg + dtype sniffs
  prep_kernel<<<198, 256, 0, stream>>>((const u16*)x, (const int*)ei, deg, flags); CK();
  // 2-5: CSR build (hist, scan, bucket)
  hist_kernel<<<N_EDGES / 256, 256, 0, stream>>>(ei, flags, deg); CK();
  scan1_kernel<<<49, 1024, 0, stream>>>(deg, offs, part, N_NODES); CK();
  scan3_kernel<<<(N_NODES + 255) / 256, 256, 0, stream>>>(offs, part, bcur, N_NODES); CK();
  bucket_kernel<<<(N_EDGES + BCHUNK - 1) / BCHUNK, 256, 0, stream>>>(ei, flags, bcur, tmp); CK();
  // 6: csr scatter (196 blocks) overlapped with layer-1 GEMM (1563 blocks)
  scatter_gemm_kernel<<<NBUCK + (N_NODES + DR - 1) / DR, 256, 0, stream>>>(
      tmp, offs, csr, x, W1, as1, ad1, flags, hbuf, ssb, sdb); CK();
  // 7: fused layer-1 aggregate(+relu) + layer-2 GEMM (2 nodes/wave, u64 gathers)
  agg_gemm_kernel<<<N_NODES / 8, 256, 0, stream>>>(hbuf, ssb, sdb, offs, csr, b1, flags,
                                                   W2, as2, ad2, hbuf2, ss2, sd2); CK();
  // 8: fused layer-2 aggregate + encoder linear
  agg_lin_kernel<<<N_NODES / 8, 256, 0, stream>>>(hbuf2, ss2, sd2, offs, csr, b2, flags,
                                                  linW, linb, zreg); CK();
  // 9: fused decoders (+pool) LAST (xhat clobbers d_out-arena scratch if !usews)
  dec_pool_kernel<<<DECB + NG, 256, 0, stream>>>(zreg, xmW1, xmb1, xmW2, xmb2,
                                                 emW1, emb1, emW2, emb2, batch, flags,
                                                 xhat, ehat, emb); CK();
#undef CK

  if (err != 0) {
    static float s_sent;
    s_sent = (float)err;
    (void)hipMemcpyAsync(d_out, &s_sent, 4, hipMemcpyHostToDevice, stream);
  }
}

// Round 6
// 344.254 us; speedup vs baseline: 1.2004x; 1.2004x over previous
//
#include <hip/hip_runtime.h>
#include <hip/hip_bf16.h>
#include <cstring>

#define N_NODES 50000
#define N_EDGES 800000
#define IN_CH 128
#define NG 500
#define OUT_ELEMS 9782000
#define NBUCK 196  // 256-node buckets: ceil(50000/256)

using bf16 = __hip_bfloat16;
typedef unsigned short u16;
typedef unsigned int u32;
typedef long long i64;
typedef unsigned long long u64;

__device__ __forceinline__ float b2f(bf16 v) { return __bfloat162float(v); }
__device__ __forceinline__ float tofl(float v) { return v; }
__device__ __forceinline__ float tofl(bf16 v) { return __bfloat162float(v); }
__device__ __forceinline__ float ldflt(const void* p, int i, int f32) {
  return f32 ? ((const float*)p)[i] : b2f(((const bf16*)p)[i]);
}
__device__ __forceinline__ int ldedge(const void* p, int i, int is64) {
  return is64 ? (int)((const i64*)p)[i] : ((const int*)p)[i];
}
__device__ __forceinline__ float sane(float v) {
  if (!isfinite(v)) return 0.f;
  return fminf(fmaxf(v, -65504.f), 65504.f);
}
__device__ __forceinline__ float lrelu(float x) { return x > 0.f ? x : 0.2f * x; }
// exact bf16->f32 unpack of a 2xbf16 word (low elem = low 16 bits)
__device__ __forceinline__ float bflo(u32 u) { return __uint_as_float(u << 16); }
__device__ __forceinline__ float bfhi(u32 u) { return __uint_as_float(u & 0xffff0000u); }

__device__ __forceinline__ float wsum(float v) {
#pragma unroll
  for (int o = 32; o > 0; o >>= 1) v += __shfl_xor(v, o, 64);
  return v;
}

// d_out is FLOAT32, 9,782,000 elems:
//   xhat@0 (6,400,000) | ehat@6,400,000 (150,000) | zreg@6,550,000 (3,200,000)
//   emb@9,750,000 (32,000)
// Scratch arena (base = d_ws if ws_size>=17.1MB else d_out; in fallback it sits
// inside the xhat region, which only the FINAL dec kernel writes):
//   deg/ss2@0 (200,000) | bcur/sd2@200,000 (200,000)
//   offs@400,000 (200,016) | part@600,016 (256) | flags@600,272 (64)
//   ss@600,448 (200,000) | sd@800,448 (200,000) | csr@1,000,448 (3,200,000)
//   hbuf(bf16)@4,200,448 (6,400,000) | tmp(u64)/hbuf2@10,600,448 (6,400,000)
//   -> ends 17,000,448 < 25,600,000

__global__ void fillsig_kernel(float* __restrict__ out, int n, float v) {
  int i = blockIdx.x * 256 + threadIdx.x;
  if (i < n) out[i] = v;
}

// ---- prep: zero deg + dtype sniffers (direct writes, no finalize pass) ----
__global__ __launch_bounds__(256) void prep_kernel(const u16* __restrict__ xb,
                                                   const int* __restrict__ ei32,
                                                   int* __restrict__ deg,
                                                   int* __restrict__ fl) {
  int bid = blockIdx.x, tid = threadIdx.x;
  if (bid < 196) {
    int i = bid * 256 + tid;
    if (i < N_NODES) deg[i] = 0;
    return;
  }
  __shared__ int c;
  if (tid == 0) c = 0;
  __syncthreads();
  int cnt = 0;
  if (bid == 196) {
#pragma unroll 4
    for (int k = 0; k < 32; ++k) {
      int i = tid + 256 * k;
      u16 u = xb[2 * i];
      int e = (u >> 7) & 0xFF;
      if (e != 0 && (e < 90 || e > 150)) ++cnt;
    }
  } else {
#pragma unroll 4
    for (int k = 0; k < 32; ++k) {
      int i = tid + 256 * k;
      if (ei32[2 * i + 1] == 0) ++cnt;
    }
  }
  atomicAdd(&c, cnt);
  __syncthreads();
  if (tid == 0) fl[bid == 196 ? 7 : 6] = c;
}

// ---- CSR build ----
__global__ void hist_kernel(const void* __restrict__ ei, const int* __restrict__ fl,
                            int* __restrict__ deg) {
  int is64 = fl[6] > 4000;
  int e = blockIdx.x * 256 + threadIdx.x;
  if (e < N_EDGES) {
    unsigned d = (unsigned)ldedge(ei, N_EDGES + e, is64);
    if (d < N_NODES) atomicAdd(&deg[d], 1);
  }
}

__global__ __launch_bounds__(1024) void scan1_kernel(const int* __restrict__ deg,
                                                     int* __restrict__ offs,
                                                     int* __restrict__ part, int n) {
  __shared__ int sm[1024];
  int t = threadIdx.x;
  int idx = blockIdx.x * 1024 + t;
  int v = (idx < n) ? deg[idx] : 0;
  sm[t] = v;
  __syncthreads();
  for (int off = 1; off < 1024; off <<= 1) {
    int add = (t >= off) ? sm[t - off] : 0;
    __syncthreads();
    sm[t] += add;
    __syncthreads();
  }
  if (idx < n) offs[idx] = sm[t] - v;
  if (t == 1023) part[blockIdx.x] = sm[1023];
}

// finalizes offs (folding the serial partial-prefix), sets offs[n], and
// initializes the 256-node-bucket cursors. part[] holds raw per-1024 sums.
__global__ void scan3_kernel(int* __restrict__ offs, const int* __restrict__ part,
                             int* __restrict__ bcur, int n) {
  __shared__ int pbase;
  int b = blockIdx.x;
  int tid = threadIdx.x;
  if (tid == 0) {
    int bucket = b >> 2;  // (b*256)>>10, constant within block
    int run = 0;
    for (int q = 0; q < bucket; ++q) run += part[q];
    pbase = run;
  }
  __syncthreads();
  int i = b * 256 + tid;
  if (i < n) {
    int v = offs[i] + pbase;
    offs[i] = v;
    if ((i & 255) == 0) bcur[i >> 8] = v;
  }
  if (i == 0) {
    int run = 0;
    for (int q = 0; q < 49; ++q) run += part[q];
    offs[n] = run;
  }
}

// Phase B: bucket-grouped edge records (256-node buckets).
#define BCHUNK 4096
__global__ __launch_bounds__(256) void bucket_kernel(const void* __restrict__ ei,
                                                     const int* __restrict__ fl,
                                                     int* __restrict__ bcur,
                                                     u64* __restrict__ tmp) {
  __shared__ int hist[NBUCK], run[NBUCK], gbase[NBUCK];
  int tid = threadIdx.x;
  if (tid < NBUCK) { hist[tid] = 0; run[tid] = 0; }
  __syncthreads();
  int is64 = fl[6] > 4000;
  int base = blockIdx.x * BCHUNK;
#pragma unroll
  for (int k = 0; k < 16; ++k) {
    int e = base + k * 256 + tid;
    if (e < N_EDGES) {
      unsigned d = (unsigned)ldedge(ei, N_EDGES + e, is64);
      if (d < N_NODES) atomicAdd(&hist[d >> 8], 1);
    }
  }
  __syncthreads();
  if (tid < NBUCK) {
    int h = hist[tid];
    gbase[tid] = h ? atomicAdd(&bcur[tid], h) : 0;
  }
  __syncthreads();
#pragma unroll
  for (int k = 0; k < 16; ++k) {
    int e = base + k * 256 + tid;
    if (e < N_EDGES) {
      unsigned d = (unsigned)ldedge(ei, N_EDGES + e, is64);
      if (d < N_NODES) {
        unsigned s = (unsigned)ldedge(ei, e, is64);
        if (s >= N_NODES) s = 0;  // keep count consistent with deg histogram
        int pos = gbase[d >> 8] + atomicAdd(&run[d >> 8], 1);
        tmp[pos] = ((u64)s << 32) | (u64)d;
      }
    }
  }
}

// Phase C: one block per 256-node bucket; L2 write locality.
__global__ __launch_bounds__(1024) void scatter2_kernel(const u64* __restrict__ tmp,
                                                        const int* __restrict__ offs,
                                                        int* __restrict__ csr) {
  __shared__ int lcur[256];
  int b = blockIdx.x;
  int tid = threadIdx.x;
  if (tid < 256) lcur[tid] = 0;
  __syncthreads();
  int nodelo = b << 8;
  int beg = offs[nodelo];
  int end = offs[min(nodelo + 256, N_NODES)];
  for (int i = beg + tid; i < end; i += 1024) {
    u64 v = tmp[i];
    int d = (int)(v & 0xFFFFFFFFu);
    int s = (int)(v >> 32);
    unsigned li = (unsigned)(d - nodelo);
    if (li < 256) {
      int pos = offs[d] + atomicAdd(&lcur[li], 1);
      if ((unsigned)pos < N_EDGES) csr[pos] = s;
    }
  }
}

// ---- GEMM + attention scores: 16 rows/block, 4 rows/wave, lane = out col ----
// Simple scalar weight loads: hipcc keeps VGPR ~40 here; manual k-quad unrolls
// measured VGPR 100-168 and halved occupancy (rounds 3-5).
template <int FIN, typename FT>
__device__ void gemm16_compute(float (&xl)[16][FIN], const void* Wv, const void* asv,
                               const void* adv, bf16* __restrict__ h, float* __restrict__ ss,
                               float* __restrict__ sd, int rbase) {
  const FT* W = (const FT*)Wv;
  const FT* as_ = (const FT*)asv;
  const FT* ad_ = (const FT*)adv;
  int lane = threadIdx.x & 63, w = threadIdx.x >> 6;
  float a_s = tofl(as_[lane]), a_d = tofl(ad_[lane]);
  int r0 = w * 4;
  float acc0 = 0.f, acc1 = 0.f, acc2 = 0.f, acc3 = 0.f;
  for (int k = 0; k < FIN; ++k) {
    float wk = tofl(W[k * 64 + lane]);
    acc0 = fmaf(xl[r0 + 0][k], wk, acc0);
    acc1 = fmaf(xl[r0 + 1][k], wk, acc1);
    acc2 = fmaf(xl[r0 + 2][k], wk, acc2);
    acc3 = fmaf(xl[r0 + 3][k], wk, acc3);
  }
  float acc[4] = {sane(acc0), sane(acc1), sane(acc2), sane(acc3)};
#pragma unroll
  for (int j = 0; j < 4; ++j) {
    int g = rbase + r0 + j;
    h[g * 64 + lane] = __float2bfloat16(acc[j]);
    float vs = wsum(acc[j] * a_s);
    float vd = wsum(acc[j] * a_d);
    if (lane == 0) { ss[g] = sane(vs); sd[g] = sane(vd); }
  }
}

// layer-1 GEMM from external x (dtype per fl[7])
template <int FIN>
__global__ __launch_bounds__(256) void gemm16_kernel(
    const void* __restrict__ xin, const void* __restrict__ W, const void* __restrict__ asrc,
    const void* __restrict__ adst, const int* __restrict__ fl, bf16* __restrict__ h,
    float* __restrict__ ss, float* __restrict__ sd) {
  __shared__ float xl[16][FIN];
  int wf = fl[7] > 2000;
  int tid = threadIdx.x;
  int rbase = blockIdx.x * 16;
  for (int i = tid; i < 16 * FIN; i += 256) {
    int rr = i / FIN, cc = i % FIN;
    xl[rr][cc] = ldflt(xin, (rbase + rr) * FIN + cc, wf);
  }
  __syncthreads();
  if (wf)
    gemm16_compute<FIN, float>(xl, W, asrc, adst, h, ss, sd, rbase);
  else
    gemm16_compute<FIN, bf16>(xl, W, asrc, adst, h, ss, sd, rbase);
}

// ---- GAT softmax-aggregate, TWO nodes per wave, 2 channels per lane ----
// Lanes 0-31 serve node dA's 64 channels as 2xbf16 words; lanes 32-63 serve
// dB. Per-edge loads/shuffles/fmas are shared by both halves. FMA order per
// channel is edge-ascending; bf16 unpack is bit-exact. (u32 gathers: the u64
// variant measured ~+13us total in round 5 -> reverted.)
__device__ __forceinline__ float2 agg_node2(const bf16* __restrict__ h,
                                            const float* __restrict__ ss,
                                            const float* __restrict__ sd,
                                            const int* __restrict__ offs,
                                            const int* __restrict__ csr, int d, int lane) {
  int hl = lane & 31;
  int hbase = lane & 32;  // own half's lane base for broadcasts
  float sdd = sd[d];
  int beg = offs[d], end = offs[d + 1];
  beg = max(0, min(beg, N_EDGES));
  end = max(beg, min(end, N_EDGES));
  float wself = __expf(fminf(lrelu(ss[d] + sdd), 60.f));
  u32 uself = ((const u32*)h)[d * 32 + hl];
  float2 acc;
  acc.x = bflo(uself) * wself;
  acc.y = bfhi(uself) * wself;
  float dpart = (hl == 0) ? wself : 0.f;
  for (int cb = beg; cb < end; cb += 32) {
    int j = cb + hl;
    int s = 0;
    float wv = 0.f;
    if (j < end) {
      s = csr[j];
      s = ((unsigned)s < N_NODES) ? s : 0;
      wv = __expf(fminf(lrelu(ss[s] + sdd), 60.f));
    }
    dpart += wv;
    int cnt = min(32, end - cb);
    for (int t0 = 0; t0 < cnt; t0 += 16) {
      u32 hv[16];
#pragma unroll
      for (int q = 0; q < 16; ++q) {
        int sq = __shfl(s, hbase + t0 + q, 64);
        hv[q] = ((const u32*)h)[sq * 32 + hl];
      }
#pragma unroll
      for (int q = 0; q < 16; ++q) {
        float wq = __shfl(wv, hbase + t0 + q, 64);
        acc.x = fmaf(bflo(hv[q]), wq, acc.x);
        acc.y = fmaf(bfhi(hv[q]), wq, acc.y);
      }
    }
  }
  // half-wide (32-lane) reduction of the denominator
#pragma unroll
  for (int o = 16; o > 0; o >>= 1) dpart += __shfl_xor(dpart, o, 64);
  float den = dpart + 1e-16f;
  acc.x = acc.x / den;
  acc.y = acc.y / den;
  return acc;
}

// ---- 4-row GEMM + scores epilogue (any single wave) ----
template <typename FT>
__device__ void gemm4_compute(float (&xl)[4][64], const void* Wv, const void* asv,
                              const void* adv, bf16* __restrict__ h, float* __restrict__ ss,
                              float* __restrict__ sd, int rbase) {
  const FT* W = (const FT*)Wv;
  const FT* as_ = (const FT*)asv;
  const FT* ad_ = (const FT*)adv;
  int lane = threadIdx.x & 63;
  float a_s = tofl(as_[lane]), a_d = tofl(ad_[lane]);
  float acc0 = 0.f, acc1 = 0.f, acc2 = 0.f, acc3 = 0.f;
  for (int k = 0; k < 64; ++k) {
    float wk = tofl(W[k * 64 + lane]);
    acc0 = fmaf(xl[0][k], wk, acc0);
    acc1 = fmaf(xl[1][k], wk, acc1);
    acc2 = fmaf(xl[2][k], wk, acc2);
    acc3 = fmaf(xl[3][k], wk, acc3);
  }
  float acc[4] = {sane(acc0), sane(acc1), sane(acc2), sane(acc3)};
#pragma unroll
  for (int j = 0; j < 4; ++j) {
    int g = rbase + j;
    h[g * 64 + lane] = __float2bfloat16(acc[j]);
    float vs = wsum(acc[j] * a_s);
    float vd = wsum(acc[j] * a_d);
    if (lane == 0) { ss[g] = sane(vs); sd[g] = sane(vd); }
  }
}

// ---- 4-row linear epilogue (any single wave) ----
template <typename FT>
__device__ void lin4_compute(float (&xl)[4][64], const void* Wv, const void* bv,
                             float* __restrict__ zio, int rbase) {
  const FT* W = (const FT*)Wv;
  const FT* b = (const FT*)bv;
  int lane = threadIdx.x & 63;
  float bl = tofl(b[lane]);
  float acc0 = bl, acc1 = bl, acc2 = bl, acc3 = bl;
  for (int k = 0; k < 64; ++k) {
    float wk = tofl(W[k * 64 + lane]);
    acc0 = fmaf(xl[0][k], wk, acc0);
    acc1 = fmaf(xl[1][k], wk, acc1);
    acc2 = fmaf(xl[2][k], wk, acc2);
    acc3 = fmaf(xl[3][k], wk, acc3);
  }
  float acc[4] = {sane(acc0), sane(acc1), sane(acc2), sane(acc3)};
#pragma unroll
  for (int j = 0; j < 4; ++j) zio[(rbase + j) * 64 + lane] = acc[j];
}

// ---- FUSED layer-1 aggregate (+relu) + layer-2 GEMM: 8 nodes/block ----
__global__ __launch_bounds__(256) void agg_gemm_kernel(
    const bf16* __restrict__ hL, const float* __restrict__ ssL, const float* __restrict__ sdL,
    const int* __restrict__ offs, const int* __restrict__ csr, const void* __restrict__ bias,
    const int* __restrict__ fl, const void* __restrict__ W2, const void* __restrict__ as2,
    const void* __restrict__ ad2, bf16* __restrict__ hOut, float* __restrict__ ssOut,
    float* __restrict__ sdOut) {
  __shared__ float o1l[8][64];
  int wf = fl[7] > 2000;
  int lane = threadIdx.x & 63, w = threadIdx.x >> 6;
  int hl = lane & 31, half = lane >> 5;
  int rbase = blockIdx.x * 8;
  int d = rbase + 2 * w + half;
  float2 r = agg_node2(hL, ssL, sdL, offs, csr, d, lane);
  float blx = ldflt(bias, 2 * hl, wf), bly = ldflt(bias, 2 * hl + 1, wf);
  o1l[2 * w + half][2 * hl] = sane(fmaxf(r.x + blx, 0.f));      // relu
  o1l[2 * w + half][2 * hl + 1] = sane(fmaxf(r.y + bly, 0.f));  // relu
  __syncthreads();
  if (w < 2) {
    float(&sub)[4][64] = *reinterpret_cast<float(*)[4][64]>(&o1l[4 * w]);
    if (wf)
      gemm4_compute<float>(sub, W2, as2, ad2, hOut, ssOut, sdOut, rbase + 4 * w);
    else
      gemm4_compute<bf16>(sub, W2, as2, ad2, hOut, ssOut, sdOut, rbase + 4 * w);
  }
}

// ---- FUSED layer-2 aggregate + encoder linear: 8 nodes/block ----
__global__ __launch_bounds__(256) void agg_lin_kernel(
    const bf16* __restrict__ hL, const float* __restrict__ ssL, const float* __restrict__ sdL,
    const int* __restrict__ offs, const int* __restrict__ csr, const void* __restrict__ bias,
    const int* __restrict__ fl, const void* __restrict__ linW, const void* __restrict__ linb,
    float* __restrict__ zreg) {
  __shared__ float o2l[8][64];
  int wf = fl[7] > 2000;
  int lane = threadIdx.x & 63, w = threadIdx.x >> 6;
  int hl = lane & 31, half = lane >> 5;
  int rbase = blockIdx.x * 8;
  int d = rbase + 2 * w + half;
  float2 r = agg_node2(hL, ssL, sdL, offs, csr, d, lane);
  float blx = ldflt(bias, 2 * hl, wf), bly = ldflt(bias, 2 * hl + 1, wf);
  o2l[2 * w + half][2 * hl] = sane(r.x + blx);      // no relu
  o2l[2 * w + half][2 * hl + 1] = sane(r.y + bly);  // no relu
  __syncthreads();
  if (w < 2) {
    float(&sub)[4][64] = *reinterpret_cast<float(*)[4][64]>(&o2l[4 * w]);
    if (wf)
      lin4_compute<float>(sub, linW, linb, zreg, rbase + 4 * w);
    else
      lin4_compute<bf16>(sub, linW, linb, zreg, rbase + 4 * w);
  }
}

// ---- global mean pool: sorted batch -> one block per graph, no atomics ----
__global__ __launch_bounds__(256) void pool_seg_kernel(const float* __restrict__ z,
                                                       const void* __restrict__ batch,
                                                       const int* __restrict__ fl,
                                                       float* __restrict__ emb) {
  __shared__ float sm[4][64];
  __shared__ int bounds[2];
  int g = blockIdx.x;
  int tid = threadIdx.x, lane = tid & 63, w = tid >> 6;
  int is64 = fl[6] > 4000;
  if (tid < 2) {
    int target = g + tid;  // lower_bound(batch, target)
    int lo = 0, hi = N_NODES;
    while (lo < hi) {
      int mid = (lo + hi) >> 1;
      if (ldedge(batch, mid, is64) < target) lo = mid + 1; else hi = mid;
    }
    bounds[tid] = lo;
  }
  __syncthreads();
  int beg = bounds[0], end = bounds[1];
  float acc = 0.f;
  for (int r = beg + w; r < end; r += 4) acc += z[r * 64 + lane];
  sm[w][lane] = acc;
  __syncthreads();
  if (w == 0) {
    float v = sm[0][lane] + sm[1][lane] + sm[2][lane] + sm[3][lane];
    float cnt = (float)max(end - beg, 1);
    emb[g * 64 + lane] = sane(v / cnt);
  }
}

// ---- decoder x_hat (64->64->128): round-2-proven scalar-load form ----
template <typename FT>
__device__ void xdec16_compute(float (&zl)[16][64], float (&t1l)[16][64], const void* W1v,
                               const void* b1v, const void* W2v, const void* b2v,
                               float* __restrict__ xout, int rbase) {
  const FT* W1 = (const FT*)W1v;
  const FT* bb1 = (const FT*)b1v;
  const FT* W2 = (const FT*)W2v;
  const FT* bb2 = (const FT*)b2v;
  int lane = threadIdx.x & 63, w = threadIdx.x >> 6;
  int r0 = w * 4;
  float b1l = tofl(bb1[lane]);
  float t0 = b1l, t1 = b1l, t2 = b1l, t3 = b1l;
  for (int k = 0; k < 64; ++k) {
    float wk = tofl(W1[k * 64 + lane]);
    t0 = fmaf(zl[r0 + 0][k], wk, t0);
    t1 = fmaf(zl[r0 + 1][k], wk, t1);
    t2 = fmaf(zl[r0 + 2][k], wk, t2);
    t3 = fmaf(zl[r0 + 3][k], wk, t3);
  }
  t1l[r0 + 0][lane] = fmaxf(t0, 0.f);
  t1l[r0 + 1][lane] = fmaxf(t1, 0.f);
  t1l[r0 + 2][lane] = fmaxf(t2, 0.f);
  t1l[r0 + 3][lane] = fmaxf(t3, 0.f);
  __syncthreads();
  float b2a = tofl(bb2[lane]), b2b = tofl(bb2[64 + lane]);
  float a0[4] = {b2a, b2a, b2a, b2a};
  float a1[4] = {b2b, b2b, b2b, b2b};
  for (int k = 0; k < 64; ++k) {
    float wa = tofl(W2[k * 128 + lane]);
    float wb = tofl(W2[k * 128 + 64 + lane]);
#pragma unroll
    for (int j = 0; j < 4; ++j) {
      float tv = t1l[r0 + j][k];
      a0[j] = fmaf(tv, wa, a0[j]);
      a1[j] = fmaf(tv, wb, a1[j]);
    }
  }
#pragma unroll
  for (int j = 0; j < 4; ++j) {
    int g = rbase + r0 + j;
    xout[g * 128 + lane] = sane(a0[j]);
    xout[g * 128 + 64 + lane] = sane(a1[j]);
  }
}

// ---- decoder e_hat (64->64->3): no cross-lane reductions ----
template <typename FT>
__device__ void edec16_compute(float (&zl)[16][64], float (&t1l)[16][65], float (&W2l)[192],
                               const void* W1v, const void* b1v, const void* b2v,
                               float* __restrict__ eout, int rbase) {
  const FT* W1 = (const FT*)W1v;
  const FT* bb1 = (const FT*)b1v;
  const FT* bb2 = (const FT*)b2v;
  int lane = threadIdx.x & 63, w = threadIdx.x >> 6;
  int r0 = w * 4;
  float b1l = tofl(bb1[lane]);
  float t0 = b1l, t1 = b1l, t2 = b1l, t3 = b1l;
  for (int k = 0; k < 64; ++k) {
    float wk = tofl(W1[k * 64 + lane]);
    t0 = fmaf(zl[r0 + 0][k], wk, t0);
    t1 = fmaf(zl[r0 + 1][k], wk, t1);
    t2 = fmaf(zl[r0 + 2][k], wk, t2);
    t3 = fmaf(zl[r0 + 3][k], wk, t3);
  }
  t1l[r0 + 0][lane] = fmaxf(t0, 0.f);
  t1l[r0 + 1][lane] = fmaxf(t1, 0.f);
  t1l[r0 + 2][lane] = fmaxf(t2, 0.f);
  t1l[r0 + 3][lane] = fmaxf(t3, 0.f);
  __syncthreads();
  int j = lane >> 4, c = lane & 15;
  if (c < 3) {
    int row = r0 + j;
    float acc = tofl(bb2[c]);
#pragma unroll 4
    for (int k = 0; k < 64; ++k) acc = fmaf(t1l[row][k], W2l[k * 3 + c], acc);
    eout[(rbase + row) * 3 + c] = sane(acc);
  }
}

// ---- FUSED decoders: one z load feeds both e_hat and x_hat ----
__global__ __launch_bounds__(256) void dec_kernel(
    const float* __restrict__ z, const void* __restrict__ xmW1, const void* __restrict__ xmb1,
    const void* __restrict__ xmW2, const void* __restrict__ xmb2, const void* __restrict__ emW1,
    const void* __restrict__ emb1, const void* __restrict__ emW2, const void* __restrict__ emb2,
    const int* __restrict__ fl, float* __restrict__ xout, float* __restrict__ eout) {
  __shared__ float zl[16][64];
  __shared__ float t1x[16][64];
  __shared__ float t1e[16][65];
  __shared__ float W2l[192];
  int wf = fl[7] > 2000;
  int tid = threadIdx.x;
  int rbase = blockIdx.x * 16;
  for (int i = tid; i < 1024; i += 256) zl[i >> 6][i & 63] = z[rbase * 64 + i];
  if (tid < 192) W2l[tid] = wf ? ((const float*)emW2)[tid] : b2f(((const bf16*)emW2)[tid]);
  __syncthreads();
  if (wf) {
    edec16_compute<float>(zl, t1e, W2l, emW1, emb1, emb2, eout, rbase);
    xdec16_compute<float>(zl, t1x, xmW1, xmb1, xmW2, xmb2, xout, rbase);
  } else {
    edec16_compute<bf16>(zl, t1e, W2l, emW1, emb1, emb2, eout, rbase);
    xdec16_compute<bf16>(zl, t1x, xmW1, xmb1, xmW2, xmb2, xout, rbase);
  }
}

extern "C" void kernel_launch(void* const* d_in, const int* in_sizes, int n_in,
                              void* d_out, int out_size, void* d_ws, size_t ws_size,
                              hipStream_t stream) {
  float* outf = (float*)d_out;
  if (out_size != OUT_ELEMS) {
    float sig = 2048.0f + fminf((float)out_size * 1e-4f, 999.f);
    fillsig_kernel<<<(out_size + 255) / 256, 256, 0, stream>>>(outf, out_size, sig);
    return;
  }
  if (n_in < 22 || in_sizes[0] != N_NODES * IN_CH || in_sizes[1] != 2 * N_EDGES) {
    fillsig_kernel<<<(out_size + 255) / 256, 256, 0, stream>>>(outf, out_size, 5000.f);
    return;
  }

  const void* x = d_in[0];
  const void* ei = d_in[1];
  const void* batch = d_in[2];
  const void* W1 = d_in[4];
  const void* as1 = d_in[5];
  const void* ad1 = d_in[6];
  const void* b1 = d_in[7];
  const void* W2 = d_in[8];
  const void* as2 = d_in[9];
  const void* ad2 = d_in[10];
  const void* b2 = d_in[11];
  const void* linW = d_in[12];
  const void* linb = d_in[13];
  const void* xmW1 = d_in[14];
  const void* xmb1 = d_in[15];
  const void* xmW2 = d_in[16];
  const void* xmb2 = d_in[17];
  const void* emW1 = d_in[18];
  const void* emb1 = d_in[19];
  const void* emW2 = d_in[20];
  const void* emb2 = d_in[21];

  float* xhat = outf;                 // [50000,128] f32
  float* ehat = outf + 6400000;       // [50000,3]
  float* zreg = outf + 6550000;       // [50000,64]  z (f32)
  float* emb = outf + 9750000;        // [500,64]

  bool usews = ws_size >= (size_t)17100000;
  char* base = usews ? (char*)d_ws : (char*)d_out;  // scratch in xhat region if !usews
  int* deg = (int*)(base + 0);
  int* bcur = (int*)(base + 200000);
  int* offs = (int*)(base + 400000);
  int* part = (int*)(base + 600016);
  int* flags = (int*)(base + 600272);
  float* ssb = (float*)(base + 600448);
  float* sdb = (float*)(base + 800448);
  int* csr = (int*)(base + 1000448);
  bf16* hbuf = (bf16*)(base + 4200448);
  u64* tmp = (u64*)(base + 10600448);  // ends 17,000,448 < 25,600,000
  // dead-region reuse after scatter2:
  float* ss2 = (float*)(base + 0);       // over deg
  float* sd2 = (float*)(base + 200000);  // over bcur
  bf16* hbuf2 = (bf16*)(base + 10600448);  // over tmp

  int err = 0, idx = 0;
  (void)hipGetLastError();
#define CK()                                                                       \
  do {                                                                             \
    ++idx;                                                                         \
    hipError_t e_ = hipGetLastError();                                             \
    if (e_ != hipSuccess && err == 0) err = 8192 + idx * 256 + ((int)e_ & 3) * 64; \
  } while (0)

  // 1: zero deg + dtype sniffs
  prep_kernel<<<198, 256, 0, stream>>>((const u16*)x, (const int*)ei, deg, flags); CK();
  // 2-6: CSR build
  hist_kernel<<<N_EDGES / 256, 256, 0, stream>>>(ei, flags, deg); CK();
  scan1_kernel<<<49, 1024, 0, stream>>>(deg, offs, part, N_NODES); CK();
  scan3_kernel<<<(N_NODES + 255) / 256, 256, 0, stream>>>(offs, part, bcur, N_NODES); CK();
  bucket_kernel<<<(N_EDGES + BCHUNK - 1) / BCHUNK, 256, 0, stream>>>(ei, flags, bcur, tmp); CK();
  scatter2_kernel<<<NBUCK, 1024, 0, stream>>>(tmp, offs, csr); CK();
  // 7: layer-1 GEMM (x @ W1) + attention scores (16 rows/block, 4/wave)
  gemm16_kernel<IN_CH><<<N_NODES / 16, 256, 0, stream>>>(x, W1, as1, ad1, flags, hbuf, ssb, sdb); CK();
  // 8: fused layer-1 aggregate(+relu) + layer-2 GEMM (2 nodes/wave, u32 gathers)
  agg_gemm_kernel<<<N_NODES / 8, 256, 0, stream>>>(hbuf, ssb, sdb, offs, csr, b1, flags,
                                                   W2, as2, ad2, hbuf2, ss2, sd2); CK();
  // 9: fused layer-2 aggregate + encoder linear
  agg_lin_kernel<<<N_NODES / 8, 256, 0, stream>>>(hbuf2, ss2, sd2, offs, csr, b2, flags,
                                                  linW, linb, zreg); CK();
  // 10: pooled embedding
  pool_seg_kernel<<<NG, 256, 0, stream>>>(zreg, batch, flags, emb); CK();
  // 11: fused decoders LAST (xhat write clobbers d_out-arena scratch if !usews)
  dec_kernel<<<N_NODES / 16, 256, 0, stream>>>(zreg, xmW1, xmb1, xmW2, xmb2,
                                               emW1, emb1, emW2, emb2, flags, xhat, ehat); CK();
#undef CK

  if (err != 0) {
    static float s_sent;
    s_sent = (float)err;
    (void)hipMemcpyAsync(d_out, &s_sent, 4, hipMemcpyHostToDevice, stream);
  }
}

// Round 8
// 332.368 us; speedup vs baseline: 1.2433x; 1.0358x over previous
//
#include <hip/hip_runtime.h>
#include <hip/hip_bf16.h>
#include <cstring>

#define N_NODES 50000
#define N_EDGES 800000
#define IN_CH 128
#define NG 500
#define OUT_ELEMS 9782000
#define NBUCK 196  // 256-node buckets: ceil(50000/256)
#define GEMMB 3125 // layer-1 gemm blocks: 50000/16
#define DECB 3125  // dec blocks: 50000/16

using bf16 = __hip_bfloat16;
typedef unsigned short u16;
typedef unsigned int u32;
typedef long long i64;
typedef unsigned long long u64;

__device__ __forceinline__ float b2f(bf16 v) { return __bfloat162float(v); }
__device__ __forceinline__ float tofl(float v) { return v; }
__device__ __forceinline__ float tofl(bf16 v) { return __bfloat162float(v); }
__device__ __forceinline__ float ldflt(const void* p, int i, int f32) {
  return f32 ? ((const float*)p)[i] : b2f(((const bf16*)p)[i]);
}
__device__ __forceinline__ int ldedge(const void* p, int i, int is64) {
  return is64 ? (int)((const i64*)p)[i] : ((const int*)p)[i];
}
__device__ __forceinline__ float sane(float v) {
  if (!isfinite(v)) return 0.f;
  return fminf(fmaxf(v, -65504.f), 65504.f);
}
__device__ __forceinline__ float lrelu(float x) { return x > 0.f ? x : 0.2f * x; }
// exact bf16->f32 unpack of a 2xbf16 word (low elem = low 16 bits)
__device__ __forceinline__ float bflo(u32 u) { return __uint_as_float(u << 16); }
__device__ __forceinline__ float bfhi(u32 u) { return __uint_as_float(u & 0xffff0000u); }

__device__ __forceinline__ float wsum(float v) {
#pragma unroll
  for (int o = 32; o > 0; o >>= 1) v += __shfl_xor(v, o, 64);
  return v;
}

// d_out is FLOAT32, 9,782,000 elems:
//   xhat@0 (6,400,000) | ehat@6,400,000 (150,000) | zreg@6,550,000 (3,200,000)
//   emb@9,750,000 (32,000)
// Scratch arena (base = d_ws if ws_size>=17.1MB else d_out; in fallback it sits
// inside the xhat region, which only the FINAL dec kernel writes):
//   deg/ss2@0 (200,000) | bcur/sd2@200,000 (200,000)
//   offs@400,000 (200,016) | part@600,016 (256) | flags@600,272 (64)
//   ss@600,448 (200,000) | sd@800,448 (200,000) | csr@1,000,448 (3,200,000)
//   hbuf(bf16)@4,200,448 (6,400,000) | tmp(u64)/hbuf2@10,600,448 (6,400,000)
//   -> ends 17,000,448 < 25,600,000

__global__ void fillsig_kernel(float* __restrict__ out, int n, float v) {
  int i = blockIdx.x * 256 + threadIdx.x;
  if (i < n) out[i] = v;
}

// ---- prep: zero deg + dtype sniffers (direct writes, no finalize pass) ----
__global__ __launch_bounds__(256) void prep_kernel(const u16* __restrict__ xb,
                                                   const int* __restrict__ ei32,
                                                   int* __restrict__ deg,
                                                   int* __restrict__ fl) {
  int bid = blockIdx.x, tid = threadIdx.x;
  if (bid < 196) {
    int i = bid * 256 + tid;
    if (i < N_NODES) deg[i] = 0;
    return;
  }
  __shared__ int c;
  if (tid == 0) c = 0;
  __syncthreads();
  int cnt = 0;
  if (bid == 196) {
#pragma unroll 4
    for (int k = 0; k < 32; ++k) {
      int i = tid + 256 * k;
      u16 u = xb[2 * i];
      int e = (u >> 7) & 0xFF;
      if (e != 0 && (e < 90 || e > 150)) ++cnt;
    }
  } else {
#pragma unroll 4
    for (int k = 0; k < 32; ++k) {
      int i = tid + 256 * k;
      if (ei32[2 * i + 1] == 0) ++cnt;
    }
  }
  atomicAdd(&c, cnt);
  __syncthreads();
  if (tid == 0) fl[bid == 196 ? 7 : 6] = c;
}

// ---- CSR build ----
__global__ void hist_kernel(const void* __restrict__ ei, const int* __restrict__ fl,
                            int* __restrict__ deg) {
  int is64 = fl[6] > 4000;
  int e = blockIdx.x * 256 + threadIdx.x;
  if (e < N_EDGES) {
    unsigned d = (unsigned)ldedge(ei, N_EDGES + e, is64);
    if (d < N_NODES) atomicAdd(&deg[d], 1);
  }
}

__global__ __launch_bounds__(1024) void scan1_kernel(const int* __restrict__ deg,
                                                     int* __restrict__ offs,
                                                     int* __restrict__ part, int n) {
  __shared__ int sm[1024];
  int t = threadIdx.x;
  int idx = blockIdx.x * 1024 + t;
  int v = (idx < n) ? deg[idx] : 0;
  sm[t] = v;
  __syncthreads();
  for (int off = 1; off < 1024; off <<= 1) {
    int add = (t >= off) ? sm[t - off] : 0;
    __syncthreads();
    sm[t] += add;
    __syncthreads();
  }
  if (idx < n) offs[idx] = sm[t] - v;
  if (t == 1023) part[blockIdx.x] = sm[1023];
}

// finalizes offs (folding the serial partial-prefix), sets offs[n], and
// initializes the 256-node-bucket cursors. part[] holds raw per-1024 sums.
__global__ void scan3_kernel(int* __restrict__ offs, const int* __restrict__ part,
                             int* __restrict__ bcur, int n) {
  __shared__ int pbase;
  int b = blockIdx.x;
  int tid = threadIdx.x;
  if (tid == 0) {
    int bucket = b >> 2;  // (b*256)>>10, constant within block
    int run = 0;
    for (int q = 0; q < bucket; ++q) run += part[q];
    pbase = run;
  }
  __syncthreads();
  int i = b * 256 + tid;
  if (i < n) {
    int v = offs[i] + pbase;
    offs[i] = v;
    if ((i & 255) == 0) bcur[i >> 8] = v;
  }
  if (i == 0) {
    int run = 0;
    for (int q = 0; q < 49; ++q) run += part[q];
    offs[n] = run;
  }
}

// ---- GEMM + attention scores body: 16 rows/block, 4 rows/wave ----
// Simple scalar weight loads: hipcc keeps VGPR ~40 here; manual k-quad unrolls
// measured VGPR 100-168 and halved occupancy (rounds 3-5).
template <int FIN, typename FT>
__device__ void gemm16_compute(float (&xl)[16][FIN], const void* Wv, const void* asv,
                               const void* adv, bf16* __restrict__ h, float* __restrict__ ss,
                               float* __restrict__ sd, int rbase) {
  const FT* W = (const FT*)Wv;
  const FT* as_ = (const FT*)asv;
  const FT* ad_ = (const FT*)adv;
  int lane = threadIdx.x & 63, w = threadIdx.x >> 6;
  float a_s = tofl(as_[lane]), a_d = tofl(ad_[lane]);
  int r0 = w * 4;
  float acc0 = 0.f, acc1 = 0.f, acc2 = 0.f, acc3 = 0.f;
  for (int k = 0; k < FIN; ++k) {
    float wk = tofl(W[k * 64 + lane]);
    acc0 = fmaf(xl[r0 + 0][k], wk, acc0);
    acc1 = fmaf(xl[r0 + 1][k], wk, acc1);
    acc2 = fmaf(xl[r0 + 2][k], wk, acc2);
    acc3 = fmaf(xl[r0 + 3][k], wk, acc3);
  }
  float acc[4] = {sane(acc0), sane(acc1), sane(acc2), sane(acc3)};
#pragma unroll
  for (int j = 0; j < 4; ++j) {
    int g = rbase + r0 + j;
    h[g * 64 + lane] = __float2bfloat16(acc[j]);
    float vs = wsum(acc[j] * a_s);
    float vd = wsum(acc[j] * a_d);
    if (lane == 0) { ss[g] = sane(vs); sd[g] = sane(vd); }
  }
}

// ---- FUSED: CSR bucket scatter (blocks 0..195) || layer-1 GEMM (196..) ----
// The two are fully independent (bucket: ei+bcur -> tmp; gemm: x+W1 -> hbuf),
// so co-dispatching overlaps their latencies: wall ~= max instead of sum.
#define BCHUNK 4096
__global__ __launch_bounds__(256) void bucket_gemm_kernel(
    const void* __restrict__ ei, int* __restrict__ bcur, u64* __restrict__ tmp,
    const void* __restrict__ xin, const void* __restrict__ W, const void* __restrict__ asrc,
    const void* __restrict__ adst, const int* __restrict__ fl, bf16* __restrict__ h,
    float* __restrict__ ss, float* __restrict__ sd) {
  __shared__ int hist[NBUCK], run[NBUCK], gbase[NBUCK];
  __shared__ float xl[16][IN_CH];
  int bid = blockIdx.x, tid = threadIdx.x;
  int is64 = fl[6] > 4000;
  int wf = fl[7] > 2000;
  if (bid < NBUCK) {
    // ---- bucket phase B: per-block LDS histogram + range reservation ----
    if (tid < NBUCK) { hist[tid] = 0; run[tid] = 0; }
    __syncthreads();
    int base = bid * BCHUNK;
#pragma unroll
    for (int k = 0; k < 16; ++k) {
      int e = base + k * 256 + tid;
      if (e < N_EDGES) {
        unsigned d = (unsigned)ldedge(ei, N_EDGES + e, is64);
        if (d < N_NODES) atomicAdd(&hist[d >> 8], 1);
      }
    }
    __syncthreads();
    if (tid < NBUCK) {
      int hh = hist[tid];
      gbase[tid] = hh ? atomicAdd(&bcur[tid], hh) : 0;
    }
    __syncthreads();
#pragma unroll
    for (int k = 0; k < 16; ++k) {
      int e = base + k * 256 + tid;
      if (e < N_EDGES) {
        unsigned d = (unsigned)ldedge(ei, N_EDGES + e, is64);
        if (d < N_NODES) {
          unsigned s = (unsigned)ldedge(ei, e, is64);
          if (s >= N_NODES) s = 0;  // keep count consistent with deg histogram
          int pos = gbase[d >> 8] + atomicAdd(&run[d >> 8], 1);
          tmp[pos] = ((u64)s << 32) | (u64)d;
        }
      }
    }
    return;
  }
  // ---- layer-1 GEMM (x @ W1) + attention scores ----
  int rbase = (bid - NBUCK) * 16;
  for (int i = tid; i < 16 * IN_CH; i += 256) {
    int rr = i / IN_CH, cc = i % IN_CH;
    xl[rr][cc] = ldflt(xin, (rbase + rr) * IN_CH + cc, wf);
  }
  __syncthreads();
  if (wf)
    gemm16_compute<IN_CH, float>(xl, W, asrc, adst, h, ss, sd, rbase);
  else
    gemm16_compute<IN_CH, bf16>(xl, W, asrc, adst, h, ss, sd, rbase);
}

// Phase C: one block per 256-node bucket; L2 write locality.
__global__ __launch_bounds__(1024) void scatter2_kernel(const u64* __restrict__ tmp,
                                                        const int* __restrict__ offs,
                                                        int* __restrict__ csr) {
  __shared__ int lcur[256];
  int b = blockIdx.x;
  int tid = threadIdx.x;
  if (tid < 256) lcur[tid] = 0;
  __syncthreads();
  int nodelo = b << 8;
  int beg = offs[nodelo];
  int end = offs[min(nodelo + 256, N_NODES)];
  for (int i = beg + tid; i < end; i += 1024) {
    u64 v = tmp[i];
    int d = (int)(v & 0xFFFFFFFFu);
    int s = (int)(v >> 32);
    unsigned li = (unsigned)(d - nodelo);
    if (li < 256) {
      int pos = offs[d] + atomicAdd(&lcur[li], 1);
      if ((unsigned)pos < N_EDGES) csr[pos] = s;
    }
  }
}

// ---- GAT softmax-aggregate, TWO nodes per wave, 2 channels per lane ----
// Lanes 0-31 serve node dA's 64 channels as 2xbf16 words; lanes 32-63 serve
// dB. Per-edge loads/shuffles/fmas are shared by both halves. FMA order per
// channel is edge-ascending; bf16 unpack is bit-exact.
__device__ __forceinline__ float2 agg_node2(const bf16* __restrict__ h,
                                            const float* __restrict__ ss,
                                            const float* __restrict__ sd,
                                            const int* __restrict__ offs,
                                            const int* __restrict__ csr, int d, int lane) {
  int hl = lane & 31;
  int hbase = lane & 32;  // own half's lane base for broadcasts
  float sdd = sd[d];
  int beg = offs[d], end = offs[d + 1];
  beg = max(0, min(beg, N_EDGES));
  end = max(beg, min(end, N_EDGES));
  float wself = __expf(fminf(lrelu(ss[d] + sdd), 60.f));
  u32 uself = ((const u32*)h)[d * 32 + hl];
  float2 acc;
  acc.x = bflo(uself) * wself;
  acc.y = bfhi(uself) * wself;
  float dpart = (hl == 0) ? wself : 0.f;
  for (int cb = beg; cb < end; cb += 32) {
    int j = cb + hl;
    int s = 0;
    float wv = 0.f;
    if (j < end) {
      s = csr[j];
      s = ((unsigned)s < N_NODES) ? s : 0;
      wv = __expf(fminf(lrelu(ss[s] + sdd), 60.f));
    }
    dpart += wv;
    int cnt = min(32, end - cb);
    for (int t0 = 0; t0 < cnt; t0 += 16) {
      u32 hv[16];
#pragma unroll
      for (int q = 0; q < 16; ++q) {
        int sq = __shfl(s, hbase + t0 + q, 64);
        hv[q] = ((const u32*)h)[sq * 32 + hl];
      }
#pragma unroll
      for (int q = 0; q < 16; ++q) {
        float wq = __shfl(wv, hbase + t0 + q, 64);
        acc.x = fmaf(bflo(hv[q]), wq, acc.x);
        acc.y = fmaf(bfhi(hv[q]), wq, acc.y);
      }
    }
  }
  // half-wide (32-lane) reduction of the denominator
#pragma unroll
  for (int o = 16; o > 0; o >>= 1) dpart += __shfl_xor(dpart, o, 64);
  float den = dpart + 1e-16f;
  acc.x = acc.x / den;
  acc.y = acc.y / den;
  return acc;
}

// ---- 2-row GEMM + scores epilogue: ALL 4 waves active (2 rows each).
// Same k-ascending FMA order as gemm4 -> bit-identical outputs. ----
template <typename FT>
__device__ void gemm2_compute(float (&xl)[8][64], int r0, const void* Wv, const void* asv,
                              const void* adv, bf16* __restrict__ h, float* __restrict__ ss,
                              float* __restrict__ sd, int rbase) {
  const FT* W = (const FT*)Wv;
  const FT* as_ = (const FT*)asv;
  const FT* ad_ = (const FT*)adv;
  int lane = threadIdx.x & 63;
  float a_s = tofl(as_[lane]), a_d = tofl(ad_[lane]);
  float acc0 = 0.f, acc1 = 0.f;
  for (int k = 0; k < 64; ++k) {
    float wk = tofl(W[k * 64 + lane]);
    acc0 = fmaf(xl[r0 + 0][k], wk, acc0);
    acc1 = fmaf(xl[r0 + 1][k], wk, acc1);
  }
  float acc[2] = {sane(acc0), sane(acc1)};
#pragma unroll
  for (int j = 0; j < 2; ++j) {
    int g = rbase + r0 + j;
    h[g * 64 + lane] = __float2bfloat16(acc[j]);
    float vs = wsum(acc[j] * a_s);
    float vd = wsum(acc[j] * a_d);
    if (lane == 0) { ss[g] = sane(vs); sd[g] = sane(vd); }
  }
}

// ---- 2-row linear epilogue: ALL 4 waves active ----
template <typename FT>
__device__ void lin2_compute(float (&xl)[8][64], int r0, const void* Wv, const void* bv,
                             float* __restrict__ zio, int rbase) {
  const FT* W = (const FT*)Wv;
  const FT* b = (const FT*)bv;
  int lane = threadIdx.x & 63;
  float bl = tofl(b[lane]);
  float acc0 = bl, acc1 = bl;
  for (int k = 0; k < 64; ++k) {
    float wk = tofl(W[k * 64 + lane]);
    acc0 = fmaf(xl[r0 + 0][k], wk, acc0);
    acc1 = fmaf(xl[r0 + 1][k], wk, acc1);
  }
  float acc[2] = {sane(acc0), sane(acc1)};
#pragma unroll
  for (int j = 0; j < 2; ++j) zio[(rbase + r0 + j) * 64 + lane] = acc[j];
}

// ---- FUSED layer-1 aggregate (+relu) + layer-2 GEMM: 8 nodes/block ----
__global__ __launch_bounds__(256) void agg_gemm_kernel(
    const bf16* __restrict__ hL, const float* __restrict__ ssL, const float* __restrict__ sdL,
    const int* __restrict__ offs, const int* __restrict__ csr, const void* __restrict__ bias,
    const int* __restrict__ fl, const void* __restrict__ W2, const void* __restrict__ as2,
    const void* __restrict__ ad2, bf16* __restrict__ hOut, float* __restrict__ ssOut,
    float* __restrict__ sdOut) {
  __shared__ float o1l[8][64];
  int wf = fl[7] > 2000;
  int lane = threadIdx.x & 63, w = threadIdx.x >> 6;
  int hl = lane & 31, half = lane >> 5;
  int rbase = blockIdx.x * 8;
  int d = rbase + 2 * w + half;
  float2 r = agg_node2(hL, ssL, sdL, offs, csr, d, lane);
  float blx = ldflt(bias, 2 * hl, wf), bly = ldflt(bias, 2 * hl + 1, wf);
  o1l[2 * w + half][2 * hl] = sane(fmaxf(r.x + blx, 0.f));      // relu
  o1l[2 * w + half][2 * hl + 1] = sane(fmaxf(r.y + bly, 0.f));  // relu
  __syncthreads();
  if (wf)
    gemm2_compute<float>(o1l, 2 * w, W2, as2, ad2, hOut, ssOut, sdOut, rbase);
  else
    gemm2_compute<bf16>(o1l, 2 * w, W2, as2, ad2, hOut, ssOut, sdOut, rbase);
}

// ---- FUSED layer-2 aggregate + encoder linear: 8 nodes/block ----
__global__ __launch_bounds__(256) void agg_lin_kernel(
    const bf16* __restrict__ hL, const float* __restrict__ ssL, const float* __restrict__ sdL,
    const int* __restrict__ offs, const int* __restrict__ csr, const void* __restrict__ bias,
    const int* __restrict__ fl, const void* __restrict__ linW, const void* __restrict__ linb,
    float* __restrict__ zreg) {
  __shared__ float o2l[8][64];
  int wf = fl[7] > 2000;
  int lane = threadIdx.x & 63, w = threadIdx.x >> 6;
  int hl = lane & 31, half = lane >> 5;
  int rbase = blockIdx.x * 8;
  int d = rbase + 2 * w + half;
  float2 r = agg_node2(hL, ssL, sdL, offs, csr, d, lane);
  float blx = ldflt(bias, 2 * hl, wf), bly = ldflt(bias, 2 * hl + 1, wf);
  o2l[2 * w + half][2 * hl] = sane(r.x + blx);      // no relu
  o2l[2 * w + half][2 * hl + 1] = sane(r.y + bly);  // no relu
  __syncthreads();
  if (wf)
    lin2_compute<float>(o2l, 2 * w, linW, linb, zreg, rbase);
  else
    lin2_compute<bf16>(o2l, 2 * w, linW, linb, zreg, rbase);
}

// ---- decoder x_hat (64->64->128): round-2-proven scalar-load form ----
template <typename FT>
__device__ void xdec16_compute(float (&zl)[16][64], float (&t1l)[16][64], const void* W1v,
                               const void* b1v, const void* W2v, const void* b2v,
                               float* __restrict__ xout, int rbase) {
  const FT* W1 = (const FT*)W1v;
  const FT* bb1 = (const FT*)b1v;
  const FT* W2 = (const FT*)W2v;
  const FT* bb2 = (const FT*)b2v;
  int lane = threadIdx.x & 63, w = threadIdx.x >> 6;
  int r0 = w * 4;
  float b1l = tofl(bb1[lane]);
  float t0 = b1l, t1 = b1l, t2 = b1l, t3 = b1l;
  for (int k = 0; k < 64; ++k) {
    float wk = tofl(W1[k * 64 + lane]);
    t0 = fmaf(zl[r0 + 0][k], wk, t0);
    t1 = fmaf(zl[r0 + 1][k], wk, t1);
    t2 = fmaf(zl[r0 + 2][k], wk, t2);
    t3 = fmaf(zl[r0 + 3][k], wk, t3);
  }
  t1l[r0 + 0][lane] = fmaxf(t0, 0.f);
  t1l[r0 + 1][lane] = fmaxf(t1, 0.f);
  t1l[r0 + 2][lane] = fmaxf(t2, 0.f);
  t1l[r0 + 3][lane] = fmaxf(t3, 0.f);
  __syncthreads();
  float b2a = tofl(bb2[lane]), b2b = tofl(bb2[64 + lane]);
  float a0[4] = {b2a, b2a, b2a, b2a};
  float a1[4] = {b2b, b2b, b2b, b2b};
  for (int k = 0; k < 64; ++k) {
    float wa = tofl(W2[k * 128 + lane]);
    float wb = tofl(W2[k * 128 + 64 + lane]);
#pragma unroll
    for (int j = 0; j < 4; ++j) {
      float tv = t1l[r0 + j][k];
      a0[j] = fmaf(tv, wa, a0[j]);
      a1[j] = fmaf(tv, wb, a1[j]);
    }
  }
#pragma unroll
  for (int j = 0; j < 4; ++j) {
    int g = rbase + r0 + j;
    xout[g * 128 + lane] = sane(a0[j]);
    xout[g * 128 + 64 + lane] = sane(a1[j]);
  }
}

// ---- decoder e_hat (64->64->3): no cross-lane reductions ----
template <typename FT>
__device__ void edec16_compute(float (&zl)[16][64], float (&t1l)[16][65], float (&W2l)[192],
                               const void* W1v, const void* b1v, const void* b2v,
                               float* __restrict__ eout, int rbase) {
  const FT* W1 = (const FT*)W1v;
  const FT* bb1 = (const FT*)b1v;
  const FT* bb2 = (const FT*)b2v;
  int lane = threadIdx.x & 63, w = threadIdx.x >> 6;
  int r0 = w * 4;
  float b1l = tofl(bb1[lane]);
  float t0 = b1l, t1 = b1l, t2 = b1l, t3 = b1l;
  for (int k = 0; k < 64; ++k) {
    float wk = tofl(W1[k * 64 + lane]);
    t0 = fmaf(zl[r0 + 0][k], wk, t0);
    t1 = fmaf(zl[r0 + 1][k], wk, t1);
    t2 = fmaf(zl[r0 + 2][k], wk, t2);
    t3 = fmaf(zl[r0 + 3][k], wk, t3);
  }
  t1l[r0 + 0][lane] = fmaxf(t0, 0.f);
  t1l[r0 + 1][lane] = fmaxf(t1, 0.f);
  t1l[r0 + 2][lane] = fmaxf(t2, 0.f);
  t1l[r0 + 3][lane] = fmaxf(t3, 0.f);
  __syncthreads();
  int j = lane >> 4, c = lane & 15;
  if (c < 3) {
    int row = r0 + j;
    float acc = tofl(bb2[c]);
#pragma unroll 4
    for (int k = 0; k < 64; ++k) acc = fmaf(t1l[row][k], W2l[k * 3 + c], acc);
    eout[(rbase + row) * 3 + c] = sane(acc);
  }
}

// ---- FUSED decoders (blocks < DECB) + global mean pool (blocks >= DECB) ----
__global__ __launch_bounds__(256) void dec_pool_kernel(
    const float* __restrict__ z, const void* __restrict__ xmW1, const void* __restrict__ xmb1,
    const void* __restrict__ xmW2, const void* __restrict__ xmb2, const void* __restrict__ emW1,
    const void* __restrict__ emb1, const void* __restrict__ emW2, const void* __restrict__ emb2,
    const void* __restrict__ batch, const int* __restrict__ fl, float* __restrict__ xout,
    float* __restrict__ eout, float* __restrict__ emb) {
  __shared__ float zl[16][64];
  __shared__ float t1x[16][64];
  __shared__ float t1e[16][65];
  __shared__ float W2l[192];
  int tid = threadIdx.x;
  if (blockIdx.x >= DECB) {
    // ---- pool branch (reuses zl/t1x LDS) ----
    float(&sm)[4][64] = *reinterpret_cast<float(*)[4][64]>(&zl[0][0]);
    int* bounds = (int*)&t1x[0][0];
    int g = blockIdx.x - DECB;
    int lane = tid & 63, w = tid >> 6;
    int is64 = fl[6] > 4000;
    if (tid < 2) {
      int target = g + tid;  // lower_bound(batch, target)
      int lo = 0, hi = N_NODES;
      while (lo < hi) {
        int mid = (lo + hi) >> 1;
        if (ldedge(batch, mid, is64) < target) lo = mid + 1; else hi = mid;
      }
      bounds[tid] = lo;
    }
    __syncthreads();
    int beg = bounds[0], end = bounds[1];
    float acc = 0.f;
    for (int r = beg + w; r < end; r += 4) acc += z[r * 64 + lane];
    sm[w][lane] = acc;
    __syncthreads();
    if (w == 0) {
      float v = sm[0][lane] + sm[1][lane] + sm[2][lane] + sm[3][lane];
      float cnt = (float)max(end - beg, 1);
      emb[g * 64 + lane] = sane(v / cnt);
    }
    return;
  }
  int wf = fl[7] > 2000;
  int rbase = blockIdx.x * 16;
  for (int i = tid; i < 1024; i += 256) zl[i >> 6][i & 63] = z[rbase * 64 + i];
  if (tid < 192) W2l[tid] = wf ? ((const float*)emW2)[tid] : b2f(((const bf16*)emW2)[tid]);
  __syncthreads();
  if (wf) {
    edec16_compute<float>(zl, t1e, W2l, emW1, emb1, emb2, eout, rbase);
    xdec16_compute<float>(zl, t1x, xmW1, xmb1, xmW2, xmb2, xout, rbase);
  } else {
    edec16_compute<bf16>(zl, t1e, W2l, emW1, emb1, emb2, eout, rbase);
    xdec16_compute<bf16>(zl, t1x, xmW1, xmb1, xmW2, xmb2, xout, rbase);
  }
}

extern "C" void kernel_launch(void* const* d_in, const int* in_sizes, int n_in,
                              void* d_out, int out_size, void* d_ws, size_t ws_size,
                              hipStream_t stream) {
  float* outf = (float*)d_out;
  if (out_size != OUT_ELEMS) {
    float sig = 2048.0f + fminf((float)out_size * 1e-4f, 999.f);
    fillsig_kernel<<<(out_size + 255) / 256, 256, 0, stream>>>(outf, out_size, sig);
    return;
  }
  if (n_in < 22 || in_sizes[0] != N_NODES * IN_CH || in_sizes[1] != 2 * N_EDGES) {
    fillsig_kernel<<<(out_size + 255) / 256, 256, 0, stream>>>(outf, out_size, 5000.f);
    return;
  }

  const void* x = d_in[0];
  const void* ei = d_in[1];
  const void* batch = d_in[2];
  const void* W1 = d_in[4];
  const void* as1 = d_in[5];
  const void* ad1 = d_in[6];
  const void* b1 = d_in[7];
  const void* W2 = d_in[8];
  const void* as2 = d_in[9];
  const void* ad2 = d_in[10];
  const void* b2 = d_in[11];
  const void* linW = d_in[12];
  const void* linb = d_in[13];
  const void* xmW1 = d_in[14];
  const void* xmb1 = d_in[15];
  const void* xmW2 = d_in[16];
  const void* xmb2 = d_in[17];
  const void* emW1 = d_in[18];
  const void* emb1 = d_in[19];
  const void* emW2 = d_in[20];
  const void* emb2 = d_in[21];

  float* xhat = outf;                 // [50000,128] f32
  float* ehat = outf + 6400000;       // [50000,3]
  float* zreg = outf + 6550000;       // [50000,64]  z (f32)
  float* emb = outf + 9750000;        // [500,64]

  bool usews = ws_size >= (size_t)17100000;
  char* base = usews ? (char*)d_ws : (char*)d_out;  // scratch in xhat region if !usews
  int* deg = (int*)(base + 0);
  int* bcur = (int*)(base + 200000);
  int* offs = (int*)(base + 400000);
  int* part = (int*)(base + 600016);
  int* flags = (int*)(base + 600272);
  float* ssb = (float*)(base + 600448);
  float* sdb = (float*)(base + 800448);
  int* csr = (int*)(base + 1000448);
  bf16* hbuf = (bf16*)(base + 4200448);
  u64* tmp = (u64*)(base + 10600448);  // ends 17,000,448 < 25,600,000
  // dead-region reuse after scatter2:
  float* ss2 = (float*)(base + 0);       // over deg
  float* sd2 = (float*)(base + 200000);  // over bcur
  bf16* hbuf2 = (bf16*)(base + 10600448);  // over tmp

  int err = 0, idx = 0;
  (void)hipGetLastError();
#define CK()                                                                       \
  do {                                                                             \
    ++idx;                                                                         \
    hipError_t e_ = hipGetLastError();                                             \
    if (e_ != hipSuccess && err == 0) err = 8192 + idx * 256 + ((int)e_ & 3) * 64; \
  } while (0)

  // 1: zero deg + dtype sniffs
  prep_kernel<<<198, 256, 0, stream>>>((const u16*)x, (const int*)ei, deg, flags); CK();
  // 2-4: degree histogram + prefix scan
  hist_kernel<<<N_EDGES / 256, 256, 0, stream>>>(ei, flags, deg); CK();
  scan1_kernel<<<49, 1024, 0, stream>>>(deg, offs, part, N_NODES); CK();
  scan3_kernel<<<(N_NODES + 255) / 256, 256, 0, stream>>>(offs, part, bcur, N_NODES); CK();
  // 5: bucket scatter (196 blocks) || layer-1 GEMM+scores (3125 blocks)
  bucket_gemm_kernel<<<NBUCK + GEMMB, 256, 0, stream>>>(
      ei, bcur, tmp, x, W1, as1, ad1, flags, hbuf, ssb, sdb); CK();
  // 6: csr scatter
  scatter2_kernel<<<NBUCK, 1024, 0, stream>>>(tmp, offs, csr); CK();
  // 7: fused layer-1 aggregate(+relu) + layer-2 GEMM (2 nodes/wave)
  agg_gemm_kernel<<<N_NODES / 8, 256, 0, stream>>>(hbuf, ssb, sdb, offs, csr, b1, flags,
                                                   W2, as2, ad2, hbuf2, ss2, sd2); CK();
  // 8: fused layer-2 aggregate + encoder linear
  agg_lin_kernel<<<N_NODES / 8, 256, 0, stream>>>(hbuf2, ss2, sd2, offs, csr, b2, flags,
                                                  linW, linb, zreg); CK();
  // 9: fused decoders + pool LAST (xhat clobbers d_out-arena scratch if !usews)
  dec_pool_kernel<<<DECB + NG, 256, 0, stream>>>(zreg, xmW1, xmb1, xmW2, xmb2,
                                                 emW1, emb1, emW2, emb2, batch, flags,
                                                 xhat, ehat, emb); CK();
#undef CK

  if (err != 0) {
    static float s_sent;
    s_sent = (float)err;
    (void)hipMemcpyAsync(d_out, &s_sent, 4, hipMemcpyHostToDevice, stream);
  }
}